// Round 1
// baseline (987.469 us; speedup 1.0000x reference)
//
#include <hip/hip_runtime.h>
#include <hip/hip_bf16.h>
#include <stdint.h>

#define Bsz 512
#define Ssz 64
#define Esz 768
#define Dsz 256
#define MROWS (Bsz * Ssz)   // 32768
#define FIN 1024

// round-to-nearest-even f32 -> bf16 bits
__device__ __forceinline__ uint32_t f2bf(float f) {
    uint32_t u = __float_as_uint(f);
    u += 0x7fffu + ((u >> 16) & 1u);
    return u >> 16;
}

// C[m,n] = sum_k A[m,k] * B(k,n) (+ bias[n])
// TRANSB: B is [N][K] row-major (Wp style). !TRANSB: B is [K][N] (corr style).
// BM=BN=128, BK=8, 256 threads, 8x8 micro-tile.
template <bool TRANSB, bool ADD_BIAS>
__global__ __launch_bounds__(256) void gemm128(const float* __restrict__ A,
                                               const float* __restrict__ Bm,
                                               const float* __restrict__ bias,
                                               float* __restrict__ C,
                                               int K, int N) {
    __shared__ __align__(16) float As[8][128];
    __shared__ __align__(16) float Bs[8][128];
    const int tid = threadIdx.x;
    const int m0 = blockIdx.y * 128;
    const int n0 = blockIdx.x * 128;
    const int tx = tid & 15;       // n micro-tile
    const int ty = tid >> 4;       // m micro-tile
    const int lrow = tid >> 1;     // 0..127
    const int lc4 = (tid & 1) * 4; // 0 or 4

    float acc[8][8];
#pragma unroll
    for (int i = 0; i < 8; i++)
#pragma unroll
        for (int j = 0; j < 8; j++) acc[i][j] = 0.f;

    for (int k0 = 0; k0 < K; k0 += 8) {
        float4 av = *(const float4*)(A + (size_t)(m0 + lrow) * K + k0 + lc4);
        float4 bv;
        if constexpr (TRANSB) {
            bv = *(const float4*)(Bm + (size_t)(n0 + lrow) * K + k0 + lc4);
        } else {
            const int krow = tid >> 5;        // 0..7
            const int c4 = (tid & 31) * 4;    // 0..124
            bv = *(const float4*)(Bm + (size_t)(k0 + krow) * N + n0 + c4);
        }
        __syncthreads();
        As[lc4 + 0][lrow] = av.x;
        As[lc4 + 1][lrow] = av.y;
        As[lc4 + 2][lrow] = av.z;
        As[lc4 + 3][lrow] = av.w;
        if constexpr (TRANSB) {
            Bs[lc4 + 0][lrow] = bv.x;
            Bs[lc4 + 1][lrow] = bv.y;
            Bs[lc4 + 2][lrow] = bv.z;
            Bs[lc4 + 3][lrow] = bv.w;
        } else {
            const int krow = tid >> 5;
            const int c4 = (tid & 31) * 4;
            *(float4*)&Bs[krow][c4] = bv;
        }
        __syncthreads();
#pragma unroll
        for (int k = 0; k < 8; k++) {
            float4 a0 = *(const float4*)&As[k][ty * 8];
            float4 a1 = *(const float4*)&As[k][ty * 8 + 4];
            float4 b0 = *(const float4*)&Bs[k][tx * 8];
            float4 b1 = *(const float4*)&Bs[k][tx * 8 + 4];
            float a_[8] = {a0.x, a0.y, a0.z, a0.w, a1.x, a1.y, a1.z, a1.w};
            float b_[8] = {b0.x, b0.y, b0.z, b0.w, b1.x, b1.y, b1.z, b1.w};
#pragma unroll
            for (int i = 0; i < 8; i++)
#pragma unroll
                for (int j = 0; j < 8; j++) acc[i][j] = fmaf(a_[i], b_[j], acc[i][j]);
        }
    }

#pragma unroll
    for (int i = 0; i < 8; i++) {
        const int m = m0 + ty * 8 + i;
#pragma unroll
        for (int j = 0; j < 8; j += 4) {
            const int n = n0 + tx * 8 + j;
            float4 v;
            v.x = acc[i][j + 0];
            v.y = acc[i][j + 1];
            v.z = acc[i][j + 2];
            v.w = acc[i][j + 3];
            if constexpr (ADD_BIAS) {
                v.x += bias[n + 0];
                v.y += bias[n + 1];
                v.z += bias[n + 2];
                v.w += bias[n + 3];
            }
            *(float4*)(C + (size_t)m * N + n) = v;
        }
    }
}

// Per (b,q): cc[i,j] = sum_e ac[b,i,e]*other[b,j,e]; write both softmaxes.
__global__ __launch_bounds__(256) void cc_softmax(const float* __restrict__ ac,
                                                  const float* __restrict__ proj1,
                                                  const float* __restrict__ proj2,
                                                  float* __restrict__ a_att,
                                                  float* __restrict__ o_att) {
    const int b = blockIdx.x, q = blockIdx.y;
    const float* __restrict__ A = ac + (size_t)b * Ssz * Dsz;
    const float* __restrict__ Bp = (q ? proj2 : proj1) + (size_t)b * Ssz * Dsz;
    __shared__ __align__(16) float As[16][64];
    __shared__ __align__(16) float Bs[16][64];
    __shared__ float sc[64][65];
    __shared__ float cmax[64], csum[64], rmax[64], rsum[64];
    const int tid = threadIdx.x;
    const int tx = tid & 15, ty = tid >> 4;
    const int lrow = tid >> 2;       // 0..63
    const int lc4 = (tid & 3) * 4;   // 0..12

    float acc[4][4];
#pragma unroll
    for (int i = 0; i < 4; i++)
#pragma unroll
        for (int j = 0; j < 4; j++) acc[i][j] = 0.f;

    for (int k0 = 0; k0 < Dsz; k0 += 16) {
        float4 av = *(const float4*)(A + lrow * Dsz + k0 + lc4);
        float4 bv = *(const float4*)(Bp + lrow * Dsz + k0 + lc4);
        __syncthreads();
        As[lc4 + 0][lrow] = av.x;
        As[lc4 + 1][lrow] = av.y;
        As[lc4 + 2][lrow] = av.z;
        As[lc4 + 3][lrow] = av.w;
        Bs[lc4 + 0][lrow] = bv.x;
        Bs[lc4 + 1][lrow] = bv.y;
        Bs[lc4 + 2][lrow] = bv.z;
        Bs[lc4 + 3][lrow] = bv.w;
        __syncthreads();
#pragma unroll
        for (int k = 0; k < 16; k++) {
            float4 a = *(const float4*)&As[k][ty * 4];
            float4 bq = *(const float4*)&Bs[k][tx * 4];
            float a_[4] = {a.x, a.y, a.z, a.w};
            float b_[4] = {bq.x, bq.y, bq.z, bq.w};
#pragma unroll
            for (int i = 0; i < 4; i++)
#pragma unroll
                for (int j = 0; j < 4; j++) acc[i][j] = fmaf(a_[i], b_[j], acc[i][j]);
        }
    }
#pragma unroll
    for (int i = 0; i < 4; i++)
#pragma unroll
        for (int j = 0; j < 4; j++) sc[ty * 4 + i][tx * 4 + j] = acc[i][j];
    __syncthreads();
    if (tid < 64) {
        const int j = tid;
        float m = -1e30f;
        for (int i = 0; i < 64; i++) m = fmaxf(m, sc[i][j]);
        float s = 0.f;
        for (int i = 0; i < 64; i++) s += __expf(sc[i][j] - m);
        cmax[j] = m;
        csum[j] = s;
    } else if (tid < 128) {
        const int i = tid - 64;
        float m = -1e30f;
        for (int j = 0; j < 64; j++) m = fmaxf(m, sc[i][j]);
        float s = 0.f;
        for (int j = 0; j < 64; j++) s += __expf(sc[i][j] - m);
        rmax[i] = m;
        rsum[i] = s;
    }
    __syncthreads();
    const int j = tid & 63;
    const int i00 = tid >> 6;
    float* __restrict__ ap = a_att + (size_t)(q * Bsz + b) * Ssz * Ssz;
    float* __restrict__ op = o_att + (size_t)(q * Bsz + b) * Ssz * Ssz;
    const float cm = cmax[j];
    const float ci = 1.f / csum[j];
    for (int i = i00; i < 64; i += 4) {
        const float v = sc[i][j];
        ap[i * 64 + j] = __expf(v - cm) * ci;
        op[i * 64 + j] = __expf(v - rmax[i]) / rsum[i];
    }
}

// Per (b,q): part0: fused[b, j, q*512 + d]       = sum_i anchor[i,d]*a_att[i,j] + anchor[j,d]
//            part1: fused[b, i, q*512 + 256 + d] = sum_j other[j,d]*o_att[i,j]  + other[i,d]
__global__ __launch_bounds__(256) void attn_apply(const float* __restrict__ proj0,
                                                  const float* __restrict__ proj1,
                                                  const float* __restrict__ proj2,
                                                  const float* __restrict__ a_att,
                                                  const float* __restrict__ o_att,
                                                  uint16_t* __restrict__ fused) {
    const int b = blockIdx.x, q = blockIdx.y;
    const float* __restrict__ anchor = proj0 + (size_t)b * Ssz * Dsz;
    const float* __restrict__ other = (q ? proj2 : proj1) + (size_t)b * Ssz * Dsz;
    __shared__ __align__(16) float att[64][68];
    __shared__ __align__(16) float Bs[16][256];
    const int tid = threadIdx.x;
    const int tx = tid & 31;   // d-tile (8 wide) -> 256
    const int ty = tid >> 5;   // 0..7 token-tile (8 wide) -> 64

    for (int part = 0; part < 2; part++) {
        const float4* __restrict__ attg =
            (const float4*)((part == 0 ? a_att : o_att) + (size_t)(q * Bsz + b) * 4096);
        const float* __restrict__ Bmat = (part == 0) ? anchor : other;
        __syncthreads();  // protect att/Bs reuse from previous part's compute
#pragma unroll
        for (int t = tid, r = 0; r < 4; t += 256, r++) {
            float4 v = attg[t];
            const int i = t >> 4, j4 = (t & 15) * 4;
            if (part == 0) {  // As[k=i][m=j] = a_att[i][j]
                att[i][j4 + 0] = v.x;
                att[i][j4 + 1] = v.y;
                att[i][j4 + 2] = v.z;
                att[i][j4 + 3] = v.w;
            } else {          // As[k=j][m=i] = o_att[i][j] transposed
                att[j4 + 0][i] = v.x;
                att[j4 + 1][i] = v.y;
                att[j4 + 2][i] = v.z;
                att[j4 + 3][i] = v.w;
            }
        }
        float acc[8][8];
#pragma unroll
        for (int i = 0; i < 8; i++)
#pragma unroll
            for (int j = 0; j < 8; j++) acc[i][j] = 0.f;

        for (int k0 = 0; k0 < 64; k0 += 16) {
            float4 bvr[4];
#pragma unroll
            for (int t = tid, r = 0; r < 4; t += 256, r++)
                bvr[r] = *(const float4*)(Bmat + (size_t)((t >> 6) + k0) * Dsz + (t & 63) * 4);
            __syncthreads();  // prev compute done (and att stores visible on first iter)
#pragma unroll
            for (int t = tid, r = 0; r < 4; t += 256, r++)
                *(float4*)&Bs[t >> 6][(t & 63) * 4] = bvr[r];
            __syncthreads();
#pragma unroll
            for (int k = 0; k < 16; k++) {
                const int kk = k0 + k;
                float4 a0 = *(const float4*)&att[kk][ty * 8];
                float4 a1 = *(const float4*)&att[kk][ty * 8 + 4];
                float4 b0 = *(const float4*)&Bs[k][tx * 8];
                float4 b1 = *(const float4*)&Bs[k][tx * 8 + 4];
                float a_[8] = {a0.x, a0.y, a0.z, a0.w, a1.x, a1.y, a1.z, a1.w};
                float b_[8] = {b0.x, b0.y, b0.z, b0.w, b1.x, b1.y, b1.z, b1.w};
#pragma unroll
                for (int i = 0; i < 8; i++)
#pragma unroll
                    for (int j = 0; j < 8; j++) acc[i][j] = fmaf(a_[i], b_[j], acc[i][j]);
            }
        }
        const int c0 = q * 512 + part * 256 + tx * 8;
#pragma unroll
        for (int r = 0; r < 8; r++) {
            const int s = ty * 8 + r;  // output token index
            float4 r0 = *(const float4*)(Bmat + (size_t)s * Dsz + tx * 8);
            float4 r1 = *(const float4*)(Bmat + (size_t)s * Dsz + tx * 8 + 4);
            const float o0 = acc[r][0] + r0.x;
            const float o1 = acc[r][1] + r0.y;
            const float o2 = acc[r][2] + r0.z;
            const float o3 = acc[r][3] + r0.w;
            const float o4 = acc[r][4] + r1.x;
            const float o5 = acc[r][5] + r1.y;
            const float o6 = acc[r][6] + r1.z;
            const float o7 = acc[r][7] + r1.w;
            uint4 pk;
            pk.x = f2bf(o0) | (f2bf(o1) << 16);
            pk.y = f2bf(o2) | (f2bf(o3) << 16);
            pk.z = f2bf(o4) | (f2bf(o5) << 16);
            pk.w = f2bf(o6) | (f2bf(o7) << 16);
            *(uint4*)(fused + (size_t)(b * 64 + s) * FIN + c0) = pk;
        }
    }
}

// h[m,o] = sum_c fused[m,c]*Wb[o,c] + bb[o]; LayerNorm over o (64); ReLU.
__global__ __launch_bounds__(256) void final_ln(const uint16_t* __restrict__ fused,
                                                const float* __restrict__ Wb,
                                                const float* __restrict__ bb,
                                                const float* __restrict__ gamma,
                                                const float* __restrict__ beta,
                                                float* __restrict__ out) {
    const int m0 = blockIdx.x * 64;
    __shared__ __align__(16) float As[16][64];
    __shared__ __align__(16) float Bs[16][64];
    __shared__ float sh[64][65];
    __shared__ float smu[64], sinv[64];
    const int tid = threadIdx.x;
    const int tx = tid & 15, ty = tid >> 4;
    const int lrow = tid >> 2;      // 0..63
    const int lc4 = (tid & 3) * 4;  // 0..12

    float acc[4][4];
#pragma unroll
    for (int i = 0; i < 4; i++)
#pragma unroll
        for (int j = 0; j < 4; j++) acc[i][j] = 0.f;

    for (int k0 = 0; k0 < FIN; k0 += 16) {
        ushort4 av = *(const ushort4*)(fused + (size_t)(m0 + lrow) * FIN + k0 + lc4);
        float4 bv = *(const float4*)(Wb + (size_t)lrow * FIN + k0 + lc4);
        __syncthreads();
        As[lc4 + 0][lrow] = __uint_as_float((uint32_t)av.x << 16);
        As[lc4 + 1][lrow] = __uint_as_float((uint32_t)av.y << 16);
        As[lc4 + 2][lrow] = __uint_as_float((uint32_t)av.z << 16);
        As[lc4 + 3][lrow] = __uint_as_float((uint32_t)av.w << 16);
        Bs[lc4 + 0][lrow] = bv.x;
        Bs[lc4 + 1][lrow] = bv.y;
        Bs[lc4 + 2][lrow] = bv.z;
        Bs[lc4 + 3][lrow] = bv.w;
        __syncthreads();
#pragma unroll
        for (int k = 0; k < 16; k++) {
            float4 a = *(const float4*)&As[k][ty * 4];
            float4 bq = *(const float4*)&Bs[k][tx * 4];
            float a_[4] = {a.x, a.y, a.z, a.w};
            float b_[4] = {bq.x, bq.y, bq.z, bq.w};
#pragma unroll
            for (int i = 0; i < 4; i++)
#pragma unroll
                for (int j = 0; j < 4; j++) acc[i][j] = fmaf(a_[i], b_[j], acc[i][j]);
        }
    }
#pragma unroll
    for (int i = 0; i < 4; i++)
#pragma unroll
        for (int j = 0; j < 4; j++) sh[ty * 4 + i][tx * 4 + j] = acc[i][j] + bb[tx * 4 + j];
    __syncthreads();
    if (tid < 64) {
        const int m = tid;
        float s = 0.f, ss = 0.f;
        for (int o = 0; o < 64; o++) {
            const float v = sh[m][o];
            s += v;
            ss += v * v;
        }
        const float mu = s * (1.f / 64.f);
        const float var = ss * (1.f / 64.f) - mu * mu;
        smu[m] = mu;
        sinv[m] = rsqrtf(var + 1e-5f);
    }
    __syncthreads();
    const int o = tid & 63;
    const int i00 = tid >> 6;
    for (int m = i00; m < 64; m += 4) {
        float v = (sh[m][o] - smu[m]) * sinv[m] * gamma[o] + beta[o];
        out[(size_t)(m0 + m) * 64 + o] = fmaxf(v, 0.f);
    }
}

extern "C" void kernel_launch(void* const* d_in, const int* in_sizes, int n_in,
                              void* d_out, int out_size, void* d_ws, size_t ws_size,
                              hipStream_t stream) {
    const float* latent0 = (const float*)d_in[0];
    const float* Wp0 = (const float*)d_in[1];
    const float* bp0 = (const float*)d_in[2];
    const float* latent1 = (const float*)d_in[3];
    const float* Wp1 = (const float*)d_in[4];
    const float* bp1 = (const float*)d_in[5];
    const float* latent2 = (const float*)d_in[6];
    const float* Wp2 = (const float*)d_in[7];
    const float* bp2 = (const float*)d_in[8];
    const float* corr = (const float*)d_in[9];
    const float* Wb = (const float*)d_in[10];
    const float* bb = (const float*)d_in[11];
    const float* gamma = (const float*)d_in[12];
    const float* beta = (const float*)d_in[13];

    float* ws = (float*)d_ws;
    float* proj0 = ws;                    // 8,388,608 floats each
    float* proj1 = ws + 8388608;
    float* proj2 = ws + 16777216;
    float* ac = ws + 25165824;            // 8,388,608
    float* a_att = ws + 33554432;         // 2 * 2,097,152
    float* o_att = ws + 37748736;         // 2 * 2,097,152
    uint16_t* fused = (uint16_t*)(ws + 41943040);  // 33,554,432 bf16

    float* out = (float*)d_out;
    dim3 blk(256);

    // projections: proj_p = latent_p @ Wp_p^T + bp_p
    dim3 gproj(Dsz / 128, MROWS / 128);
    gemm128<true, true><<<gproj, blk, 0, stream>>>(latent0, Wp0, bp0, proj0, Esz, Dsz);
    gemm128<true, true><<<gproj, blk, 0, stream>>>(latent1, Wp1, bp1, proj1, Esz, Dsz);
    gemm128<true, true><<<gproj, blk, 0, stream>>>(latent2, Wp2, bp2, proj2, Esz, Dsz);

    // ac = proj0 @ corr   ([K][N] B layout)
    dim3 gac(Dsz / 128, MROWS / 128);
    gemm128<false, false><<<gac, blk, 0, stream>>>(proj0, corr, (const float*)nullptr, ac, Dsz, Dsz);

    // cc + both softmaxes
    cc_softmax<<<dim3(Bsz, 2), blk, 0, stream>>>(ac, proj1, proj2, a_att, o_att);

    // attention apply -> fused (bf16)
    attn_apply<<<dim3(Bsz, 2), blk, 0, stream>>>(proj0, proj1, proj2, a_att, o_att, fused);

    // bottleneck GEMM + LayerNorm + ReLU
    final_ln<<<MROWS / 64, blk, 0, stream>>>(fused, Wb, bb, gamma, beta, out);

    (void)in_sizes; (void)n_in; (void)out_size; (void)ws_size;
}

// Round 2
// 750.026 us; speedup vs baseline: 1.3166x; 1.3166x over previous
//
#include <hip/hip_runtime.h>
#include <hip/hip_bf16.h>
#include <stdint.h>

#define Bsz 512
#define Ssz 64
#define Esz 768
#define Dsz 256
#define MROWS (Bsz * Ssz)   // 32768
#define FIN 1024

typedef _Float16 f16;
typedef f16 f16x4 __attribute__((ext_vector_type(4)));
typedef f16 f16x8v __attribute__((ext_vector_type(8)));
typedef float f32x4 __attribute__((ext_vector_type(4)));

// round-to-nearest-even f32 -> bf16 bits
__device__ __forceinline__ uint32_t f2bf(float f) {
    uint32_t u = __float_as_uint(f);
    u += 0x7fffu + ((u >> 16) & 1u);
    return u >> 16;
}

// ---------------------------------------------------------------------------
// prep: Wp (3x[256][768] f32) -> f16; corr [256][256] f32 -> corrT f16 [e][d]
__global__ __launch_bounds__(256) void prep(const float* __restrict__ Wp0,
                                            const float* __restrict__ Wp1,
                                            const float* __restrict__ Wp2,
                                            const float* __restrict__ corr,
                                            f16* __restrict__ Wph,
                                            f16* __restrict__ corrT) {
    const int t = blockIdx.x * 256 + threadIdx.x;
    if (t < 3 * 196608) {
        const int z = t / 196608, i = t % 196608;
        const float* W = (z == 0) ? Wp0 : (z == 1) ? Wp1 : Wp2;
        Wph[(size_t)z * 196608 + i] = (f16)W[i];
    }
    if (t < 65536) {
        const int d = t >> 8, e = t & 255;
        corrT[e * 256 + d] = (f16)corr[d * 256 + e];
    }
}

// ---------------------------------------------------------------------------
// MFMA GEMM: C[m,n] = sum_k A[m,k] * B[n,k]  (B given [N][K] row-major, f16)
// Output f16 [M][256]. Tile 128x128xBK64, 256 threads = 4 waves, wave 64x64.
// A is fp32 (converted in staging) or fp16. blockIdx.z selects modality.
template <bool A_F16, bool BIAS>
__global__ __launch_bounds__(256, 2) void mfma_gemm(
    const float* __restrict__ A32a, const float* __restrict__ A32b,
    const float* __restrict__ A32c, const f16* __restrict__ A16,
    const f16* __restrict__ Bh, const float* __restrict__ biasA,
    const float* __restrict__ biasB, const float* __restrict__ biasC,
    f16* __restrict__ Ch, int K) {
    const int tid = threadIdx.x;
    const int n0 = blockIdx.x * 128;
    const int m0 = blockIdx.y * 128;
    const int z = blockIdx.z;
    const float* A32 = (z == 0) ? A32a : (z == 1) ? A32b : A32c;
    const float* bias = (z == 0) ? biasA : (z == 1) ? biasB : biasC;
    const f16* Bz = Bh + (size_t)z * 256 * K;
    f16* Cz = Ch + (size_t)z * MROWS * 256;

    // fragment-contiguous LDS: [kh(2)][sub(8)][lane(64)][j(8)] f16
    __shared__ __align__(16) f16 AhS[2 * 8 * 64 * 8];
    __shared__ __align__(16) f16 BhS[2 * 8 * 64 * 8];

    const int lane = tid & 63;
    const int w = tid >> 6;
    const int ma = (w >> 1) * 4;  // wave's first m-sub (of 8)
    const int nb = (w & 1) * 4;   // wave's first n-sub (of 8)

    f32x4 acc[4][4];
#pragma unroll
    for (int i = 0; i < 4; i++)
#pragma unroll
        for (int j = 0; j < 4; j++) acc[i][j] = (f32x4){0.f, 0.f, 0.f, 0.f};

    for (int k0 = 0; k0 < K; k0 += 64) {
        float4 aLo[4], aHi[4];
        uint4 aLd[4], bLd[4];
#pragma unroll
        for (int r = 0; r < 4; r++) {
            const int s = tid + 256 * r;
            const int mm = s & 127, k8 = s >> 7;
            if constexpr (A_F16) {
                aLd[r] = *(const uint4*)(A16 + (size_t)(m0 + mm) * K + k0 + k8 * 8);
            } else {
                const float* p = A32 + (size_t)(m0 + mm) * K + k0 + k8 * 8;
                aLo[r] = *(const float4*)p;
                aHi[r] = *(const float4*)(p + 4);
            }
            bLd[r] = *(const uint4*)(Bz + (size_t)(n0 + mm) * K + k0 + k8 * 8);
        }
        __syncthreads();  // previous iter's frag reads complete
#pragma unroll
        for (int r = 0; r < 4; r++) {
            const int s = tid + 256 * r;
            const int mm = s & 127, k8 = s >> 7;
            const int idx = ((((k8 >> 2) * 8) + (mm >> 4)) * 64 + (mm & 15) + 16 * (k8 & 3)) * 8;
            if constexpr (A_F16) {
                *(uint4*)&AhS[idx] = aLd[r];
            } else {
                f16x8v h;
                h[0] = (f16)aLo[r].x; h[1] = (f16)aLo[r].y;
                h[2] = (f16)aLo[r].z; h[3] = (f16)aLo[r].w;
                h[4] = (f16)aHi[r].x; h[5] = (f16)aHi[r].y;
                h[6] = (f16)aHi[r].z; h[7] = (f16)aHi[r].w;
                *(f16x8v*)&AhS[idx] = h;
            }
            *(uint4*)&BhS[idx] = bLd[r];
        }
        __syncthreads();
#pragma unroll
        for (int kh = 0; kh < 2; kh++) {
            f16x8v af[4], bf[4];
#pragma unroll
            for (int i = 0; i < 4; i++)
                af[i] = *(const f16x8v*)&AhS[((kh * 8 + ma + i) * 64 + lane) * 8];
#pragma unroll
            for (int j = 0; j < 4; j++)
                bf[j] = *(const f16x8v*)&BhS[((kh * 8 + nb + j) * 64 + lane) * 8];
#pragma unroll
            for (int i = 0; i < 4; i++)
#pragma unroll
                for (int j = 0; j < 4; j++)
                    acc[i][j] = __builtin_amdgcn_mfma_f32_16x16x32_f16(af[i], bf[j], acc[i][j], 0, 0, 0);
        }
    }

    // epilogue: C/D frag mapping col=lane&15, row=(lane>>4)*4+reg
    const int cr = lane & 15, qr = lane >> 4;
    const int mw = m0 + (w >> 1) * 64;
    const int nw = n0 + (w & 1) * 64;
#pragma unroll
    for (int i = 0; i < 4; i++) {
#pragma unroll
        for (int j = 0; j < 4; j++) {
            const int col = nw + j * 16 + cr;
            const float bv = BIAS ? bias[col] : 0.f;
#pragma unroll
            for (int r = 0; r < 4; r++) {
                const int row = mw + i * 16 + qr * 4 + r;
                Cz[(size_t)row * 256 + col] = (f16)(acc[i][j][r] + bv);
            }
        }
    }
}

// ---------------------------------------------------------------------------
// Per (b,q): cc[i,j] = sum_e ac[b,i,e]*other[b,j,e]; write both softmaxes.
__global__ __launch_bounds__(256) void cc_softmax(const f16* __restrict__ ac,
                                                  const f16* __restrict__ proj1,
                                                  const f16* __restrict__ proj2,
                                                  float* __restrict__ a_att,
                                                  float* __restrict__ o_att) {
    const int b = blockIdx.x, q = blockIdx.y;
    const f16* __restrict__ A = ac + (size_t)b * Ssz * Dsz;
    const f16* __restrict__ Bp = (q ? proj2 : proj1) + (size_t)b * Ssz * Dsz;
    __shared__ __align__(16) float As[16][64];
    __shared__ __align__(16) float Bs[16][64];
    __shared__ float sc[64][65];
    __shared__ float cmax[64], csum[64], rmax[64], rsum[64];
    const int tid = threadIdx.x;
    const int tx = tid & 15, ty = tid >> 4;
    const int lrow = tid >> 2;       // 0..63
    const int lc4 = (tid & 3) * 4;   // 0..12

    float acc[4][4];
#pragma unroll
    for (int i = 0; i < 4; i++)
#pragma unroll
        for (int j = 0; j < 4; j++) acc[i][j] = 0.f;

    for (int k0 = 0; k0 < Dsz; k0 += 16) {
        f16x4 av = *(const f16x4*)(A + lrow * Dsz + k0 + lc4);
        f16x4 bv = *(const f16x4*)(Bp + lrow * Dsz + k0 + lc4);
        __syncthreads();
        As[lc4 + 0][lrow] = (float)av.x;
        As[lc4 + 1][lrow] = (float)av.y;
        As[lc4 + 2][lrow] = (float)av.z;
        As[lc4 + 3][lrow] = (float)av.w;
        Bs[lc4 + 0][lrow] = (float)bv.x;
        Bs[lc4 + 1][lrow] = (float)bv.y;
        Bs[lc4 + 2][lrow] = (float)bv.z;
        Bs[lc4 + 3][lrow] = (float)bv.w;
        __syncthreads();
#pragma unroll
        for (int k = 0; k < 16; k++) {
            float4 a = *(const float4*)&As[k][ty * 4];
            float4 bq = *(const float4*)&Bs[k][tx * 4];
            float a_[4] = {a.x, a.y, a.z, a.w};
            float b_[4] = {bq.x, bq.y, bq.z, bq.w};
#pragma unroll
            for (int i = 0; i < 4; i++)
#pragma unroll
                for (int j = 0; j < 4; j++) acc[i][j] = fmaf(a_[i], b_[j], acc[i][j]);
        }
    }
#pragma unroll
    for (int i = 0; i < 4; i++)
#pragma unroll
        for (int j = 0; j < 4; j++) sc[ty * 4 + i][tx * 4 + j] = acc[i][j];
    __syncthreads();
    if (tid < 64) {
        const int j = tid;
        float m = -1e30f;
        for (int i = 0; i < 64; i++) m = fmaxf(m, sc[i][j]);
        float s = 0.f;
        for (int i = 0; i < 64; i++) s += __expf(sc[i][j] - m);
        cmax[j] = m;
        csum[j] = s;
    } else if (tid < 128) {
        const int i = tid - 64;
        float m = -1e30f;
        for (int j = 0; j < 64; j++) m = fmaxf(m, sc[i][j]);
        float s = 0.f;
        for (int j = 0; j < 64; j++) s += __expf(sc[i][j] - m);
        rmax[i] = m;
        rsum[i] = s;
    }
    __syncthreads();
    const int j = tid & 63;
    const int i00 = tid >> 6;
    float* __restrict__ ap = a_att + (size_t)(q * Bsz + b) * Ssz * Ssz;
    float* __restrict__ op = o_att + (size_t)(q * Bsz + b) * Ssz * Ssz;
    const float cm = cmax[j];
    const float ci = 1.f / csum[j];
    for (int i = i00; i < 64; i += 4) {
        const float v = sc[i][j];
        ap[i * 64 + j] = __expf(v - cm) * ci;
        op[i * 64 + j] = __expf(v - rmax[i]) / rsum[i];
    }
}

// ---------------------------------------------------------------------------
// Per (b,q): part0: fused[b, j, q*512 + d]       = sum_i anchor[i,d]*a_att[i,j] + anchor[j,d]
//            part1: fused[b, i, q*512 + 256 + d] = sum_j other[j,d]*o_att[i,j]  + other[i,d]
__global__ __launch_bounds__(256) void attn_apply(const f16* __restrict__ proj0,
                                                  const f16* __restrict__ proj1,
                                                  const f16* __restrict__ proj2,
                                                  const float* __restrict__ a_att,
                                                  const float* __restrict__ o_att,
                                                  uint16_t* __restrict__ fused) {
    const int b = blockIdx.x, q = blockIdx.y;
    const f16* __restrict__ anchor = proj0 + (size_t)b * Ssz * Dsz;
    const f16* __restrict__ other = (q ? proj2 : proj1) + (size_t)b * Ssz * Dsz;
    __shared__ __align__(16) float att[64][68];
    __shared__ __align__(16) float Bs[16][256];
    const int tid = threadIdx.x;
    const int tx = tid & 31;   // d-tile (8 wide) -> 256
    const int ty = tid >> 5;   // 0..7 token-tile (8 wide) -> 64

    for (int part = 0; part < 2; part++) {
        const float4* __restrict__ attg =
            (const float4*)((part == 0 ? a_att : o_att) + (size_t)(q * Bsz + b) * 4096);
        const f16* __restrict__ Bmat = (part == 0) ? anchor : other;
        __syncthreads();  // protect att/Bs reuse from previous part's compute
#pragma unroll
        for (int t = tid, r = 0; r < 4; t += 256, r++) {
            float4 v = attg[t];
            const int i = t >> 4, j4 = (t & 15) * 4;
            if (part == 0) {  // As[k=i][m=j] = a_att[i][j]
                att[i][j4 + 0] = v.x;
                att[i][j4 + 1] = v.y;
                att[i][j4 + 2] = v.z;
                att[i][j4 + 3] = v.w;
            } else {          // As[k=j][m=i] = o_att[i][j] transposed
                att[j4 + 0][i] = v.x;
                att[j4 + 1][i] = v.y;
                att[j4 + 2][i] = v.z;
                att[j4 + 3][i] = v.w;
            }
        }
        float acc[8][8];
#pragma unroll
        for (int i = 0; i < 8; i++)
#pragma unroll
            for (int j = 0; j < 8; j++) acc[i][j] = 0.f;

        for (int k0 = 0; k0 < 64; k0 += 16) {
            f16x4 bvr[4];
#pragma unroll
            for (int t = tid, r = 0; r < 4; t += 256, r++)
                bvr[r] = *(const f16x4*)(Bmat + (size_t)((t >> 6) + k0) * Dsz + (t & 63) * 4);
            __syncthreads();  // prev compute done (and att stores visible on first iter)
#pragma unroll
            for (int t = tid, r = 0; r < 4; t += 256, r++) {
                float4 fv;
                fv.x = (float)bvr[r].x;
                fv.y = (float)bvr[r].y;
                fv.z = (float)bvr[r].z;
                fv.w = (float)bvr[r].w;
                *(float4*)&Bs[t >> 6][(t & 63) * 4] = fv;
            }
            __syncthreads();
#pragma unroll
            for (int k = 0; k < 16; k++) {
                const int kk = k0 + k;
                float4 a0 = *(const float4*)&att[kk][ty * 8];
                float4 a1 = *(const float4*)&att[kk][ty * 8 + 4];
                float4 b0 = *(const float4*)&Bs[k][tx * 8];
                float4 b1 = *(const float4*)&Bs[k][tx * 8 + 4];
                float a_[8] = {a0.x, a0.y, a0.z, a0.w, a1.x, a1.y, a1.z, a1.w};
                float b_[8] = {b0.x, b0.y, b0.z, b0.w, b1.x, b1.y, b1.z, b1.w};
#pragma unroll
                for (int i = 0; i < 8; i++)
#pragma unroll
                    for (int j = 0; j < 8; j++) acc[i][j] = fmaf(a_[i], b_[j], acc[i][j]);
            }
        }
        const int c0 = q * 512 + part * 256 + tx * 8;
#pragma unroll
        for (int r = 0; r < 8; r++) {
            const int s = ty * 8 + r;  // output token index
            f16x8v rv = *(const f16x8v*)(Bmat + (size_t)s * Dsz + tx * 8);
            uint4 pk;
            pk.x = f2bf(acc[r][0] + (float)rv[0]) | (f2bf(acc[r][1] + (float)rv[1]) << 16);
            pk.y = f2bf(acc[r][2] + (float)rv[2]) | (f2bf(acc[r][3] + (float)rv[3]) << 16);
            pk.z = f2bf(acc[r][4] + (float)rv[4]) | (f2bf(acc[r][5] + (float)rv[5]) << 16);
            pk.w = f2bf(acc[r][6] + (float)rv[6]) | (f2bf(acc[r][7] + (float)rv[7]) << 16);
            *(uint4*)(fused + (size_t)(b * 64 + s) * FIN + c0) = pk;
        }
    }
}

// ---------------------------------------------------------------------------
// h[m,o] = sum_c fused[m,c]*Wb[o,c] + bb[o]; LayerNorm over o (64); ReLU.
__global__ __launch_bounds__(256) void final_ln(const uint16_t* __restrict__ fused,
                                                const float* __restrict__ Wb,
                                                const float* __restrict__ bb,
                                                const float* __restrict__ gamma,
                                                const float* __restrict__ beta,
                                                float* __restrict__ out) {
    const int m0 = blockIdx.x * 64;
    __shared__ __align__(16) float As[16][64];
    __shared__ __align__(16) float Bs[16][64];
    __shared__ float sh[64][65];
    __shared__ float smu[64], sinv[64];
    const int tid = threadIdx.x;
    const int tx = tid & 15, ty = tid >> 4;
    const int lrow = tid >> 2;      // 0..63
    const int lc4 = (tid & 3) * 4;  // 0..12

    float acc[4][4];
#pragma unroll
    for (int i = 0; i < 4; i++)
#pragma unroll
        for (int j = 0; j < 4; j++) acc[i][j] = 0.f;

    for (int k0 = 0; k0 < FIN; k0 += 16) {
        ushort4 av = *(const ushort4*)(fused + (size_t)(m0 + lrow) * FIN + k0 + lc4);
        float4 bv = *(const float4*)(Wb + (size_t)lrow * FIN + k0 + lc4);
        __syncthreads();
        As[lc4 + 0][lrow] = __uint_as_float((uint32_t)av.x << 16);
        As[lc4 + 1][lrow] = __uint_as_float((uint32_t)av.y << 16);
        As[lc4 + 2][lrow] = __uint_as_float((uint32_t)av.z << 16);
        As[lc4 + 3][lrow] = __uint_as_float((uint32_t)av.w << 16);
        Bs[lc4 + 0][lrow] = bv.x;
        Bs[lc4 + 1][lrow] = bv.y;
        Bs[lc4 + 2][lrow] = bv.z;
        Bs[lc4 + 3][lrow] = bv.w;
        __syncthreads();
#pragma unroll
        for (int k = 0; k < 16; k++) {
            float4 a = *(const float4*)&As[k][ty * 4];
            float4 bq = *(const float4*)&Bs[k][tx * 4];
            float a_[4] = {a.x, a.y, a.z, a.w};
            float b_[4] = {bq.x, bq.y, bq.z, bq.w};
#pragma unroll
            for (int i = 0; i < 4; i++)
#pragma unroll
                for (int j = 0; j < 4; j++) acc[i][j] = fmaf(a_[i], b_[j], acc[i][j]);
        }
    }
#pragma unroll
    for (int i = 0; i < 4; i++)
#pragma unroll
        for (int j = 0; j < 4; j++) sh[ty * 4 + i][tx * 4 + j] = acc[i][j] + bb[tx * 4 + j];
    __syncthreads();
    if (tid < 64) {
        const int m = tid;
        float s = 0.f, ss = 0.f;
        for (int o = 0; o < 64; o++) {
            const float v = sh[m][o];
            s += v;
            ss += v * v;
        }
        const float mu = s * (1.f / 64.f);
        const float var = ss * (1.f / 64.f) - mu * mu;
        smu[m] = mu;
        sinv[m] = rsqrtf(var + 1e-5f);
    }
    __syncthreads();
    const int o = tid & 63;
    const int i00 = tid >> 6;
    for (int m = i00; m < 64; m += 4) {
        float v = (sh[m][o] - smu[m]) * sinv[m] * gamma[o] + beta[o];
        out[(size_t)(m0 + m) * 64 + o] = fmaxf(v, 0.f);
    }
}

extern "C" void kernel_launch(void* const* d_in, const int* in_sizes, int n_in,
                              void* d_out, int out_size, void* d_ws, size_t ws_size,
                              hipStream_t stream) {
    const float* latent0 = (const float*)d_in[0];
    const float* Wp0 = (const float*)d_in[1];
    const float* bp0 = (const float*)d_in[2];
    const float* latent1 = (const float*)d_in[3];
    const float* Wp1 = (const float*)d_in[4];
    const float* bp1 = (const float*)d_in[5];
    const float* latent2 = (const float*)d_in[6];
    const float* Wp2 = (const float*)d_in[7];
    const float* bp2 = (const float*)d_in[8];
    const float* corr = (const float*)d_in[9];
    const float* Wb = (const float*)d_in[10];
    const float* bb = (const float*)d_in[11];
    const float* gamma = (const float*)d_in[12];
    const float* beta = (const float*)d_in[13];

    char* ws = (char*)d_ws;
    f16* proj_h = (f16*)ws;                               // 3 * 16 MB
    f16* ac_h = (f16*)(ws + 48ull * 1024 * 1024);         // 16 MB
    float* a_att = (float*)(ws + 64ull * 1024 * 1024);    // 16 MB
    float* o_att = (float*)(ws + 80ull * 1024 * 1024);    // 16 MB
    uint16_t* fused = (uint16_t*)(ws + 96ull * 1024 * 1024);  // 64 MB
    f16* Wph = (f16*)(ws + 160ull * 1024 * 1024);         // 1.125 MB
    f16* corrT = (f16*)(ws + 162ull * 1024 * 1024);       // 128 KB

    float* out = (float*)d_out;
    dim3 blk(256);

    // pre-convert weights
    prep<<<2304, blk, 0, stream>>>(Wp0, Wp1, Wp2, corr, Wph, corrT);

    // projections: proj_h[z] = latent_z @ Wp_z^T + bp_z   (fp16 MFMA)
    mfma_gemm<false, true><<<dim3(2, 256, 3), blk, 0, stream>>>(
        latent0, latent1, latent2, (const f16*)nullptr, Wph, bp0, bp1, bp2, proj_h, Esz);

    // ac = proj0 @ corr  (B = corrT [e][d] f16)
    mfma_gemm<true, false><<<dim3(2, 256, 1), blk, 0, stream>>>(
        (const float*)nullptr, (const float*)nullptr, (const float*)nullptr, proj_h,
        corrT, (const float*)nullptr, (const float*)nullptr, (const float*)nullptr,
        ac_h, Dsz);

    const f16* proj1_h = proj_h + (size_t)MROWS * 256;
    const f16* proj2_h = proj_h + 2ull * MROWS * 256;

    // cc + both softmaxes
    cc_softmax<<<dim3(Bsz, 2), blk, 0, stream>>>(ac_h, proj1_h, proj2_h, a_att, o_att);

    // attention apply -> fused (bf16)
    attn_apply<<<dim3(Bsz, 2), blk, 0, stream>>>(proj_h, proj1_h, proj2_h, a_att, o_att, fused);

    // bottleneck GEMM + LayerNorm + ReLU
    final_ln<<<MROWS / 64, blk, 0, stream>>>(fused, Wb, bb, gamma, beta, out);

    (void)in_sizes; (void)n_in; (void)out_size; (void)ws_size;
}

// Round 3
// 550.760 us; speedup vs baseline: 1.7929x; 1.3618x over previous
//
#include <hip/hip_runtime.h>
#include <hip/hip_bf16.h>
#include <stdint.h>

#define Bsz 512
#define Ssz 64
#define Esz 768
#define Dsz 256
#define MROWS (Bsz * Ssz)   // 32768
#define FIN 1024

typedef _Float16 f16;
typedef f16 f16x4 __attribute__((ext_vector_type(4)));
typedef f16 f16x8v __attribute__((ext_vector_type(8)));
typedef float f32x4 __attribute__((ext_vector_type(4)));

// round-to-nearest-even f32 -> bf16 bits
__device__ __forceinline__ uint32_t f2bf(float f) {
    uint32_t u = __float_as_uint(f);
    u += 0x7fffu + ((u >> 16) & 1u);
    return u >> 16;
}

// ---------------------------------------------------------------------------
// prep: Wp (3x[256][768] f32) -> f16; corr [256][256] f32 -> corrT f16 [e][d]
__global__ __launch_bounds__(256) void prep(const float* __restrict__ Wp0,
                                            const float* __restrict__ Wp1,
                                            const float* __restrict__ Wp2,
                                            const float* __restrict__ corr,
                                            f16* __restrict__ Wph,
                                            f16* __restrict__ corrT) {
    const int t = blockIdx.x * 256 + threadIdx.x;
    if (t < 3 * 196608) {
        const int z = t / 196608, i = t % 196608;
        const float* W = (z == 0) ? Wp0 : (z == 1) ? Wp1 : Wp2;
        Wph[(size_t)z * 196608 + i] = (f16)W[i];
    }
    if (t < 65536) {
        const int d = t >> 8, e = t & 255;
        corrT[e * 256 + d] = (f16)corr[d * 256 + e];
    }
}

// ---------------------------------------------------------------------------
// MFMA GEMM: C[m,n] = sum_k A[m,k] * B[n,k]  (B given [N][K] row-major, f16)
// Output f16 [M][256]. Tile 128x128xBK64, 256 threads = 4 waves, wave 64x64.
// LDS staging is fragment-contiguous [kh][sub16][lane][8]f16, 16B-unit index
// swizzled ^(k8&3) to break staging-write bank conflicts.
// Staging loads are flat-coalesced: f=r*256+tid, row=f>>3, c8=f&7.
// No registers held across barriers (R2 spilled ~290MB to scratch).
template <bool A_F16, bool BIAS>
__global__ __launch_bounds__(256) void mfma_gemm(
    const float* __restrict__ A32a, const float* __restrict__ A32b,
    const float* __restrict__ A32c, const f16* __restrict__ A16,
    const f16* __restrict__ Bh, const float* __restrict__ biasA,
    const float* __restrict__ biasB, const float* __restrict__ biasC,
    f16* __restrict__ Ch, int K) {
    const int tid = threadIdx.x;
    const int n0 = blockIdx.x * 128;
    const int m0 = blockIdx.y * 128;
    const int z = blockIdx.z;
    const float* A32 = (z == 0) ? A32a : (z == 1) ? A32b : A32c;
    const float* bias = (z == 0) ? biasA : (z == 1) ? biasB : biasC;
    const f16* Bz = Bh + (size_t)z * 256 * K;
    f16* Cz = Ch + (size_t)z * MROWS * 256;

    __shared__ __align__(16) f16 AhS[8192];  // 16 KB
    __shared__ __align__(16) f16 BhS[8192];  // 16 KB

    const int lane = tid & 63;
    const int w = tid >> 6;
    const int ma = (w >> 1) * 4;  // wave's first m-sub (of 8)
    const int nb = (w & 1) * 4;   // wave's first n-sub (of 8)

    // staging decomposition (same every iter)
    const int srow = tid >> 3;      // 0..31 (+32 per rep)
    const int sc8 = tid & 7;        // 0..7

    f32x4 acc[4][4];
#pragma unroll
    for (int i = 0; i < 4; i++)
#pragma unroll
        for (int j = 0; j < 4; j++) acc[i][j] = (f32x4){0.f, 0.f, 0.f, 0.f};

    for (int k0 = 0; k0 < K; k0 += 64) {
        __syncthreads();  // previous iter's fragment reads complete
#pragma unroll
        for (int r = 0; r < 4; r++) {
            const int row = srow + 32 * r;
            // 16B-unit index, swizzled
            const int unit = (((sc8 >> 2) * 8 + (row >> 4)) * 64 + (row & 15) + 16 * (sc8 & 3)) ^ (sc8 & 3);
            if constexpr (A_F16) {
                uint4 av = *(const uint4*)(A16 + (size_t)(m0 + row) * K + k0 + sc8 * 8);
                *(uint4*)&AhS[unit * 8] = av;
            } else {
                const float* p = A32 + (size_t)(m0 + row) * K + k0 + sc8 * 8;
                float4 lo = *(const float4*)p;
                float4 hi = *(const float4*)(p + 4);
                f16x8v h;
                h[0] = (f16)lo.x; h[1] = (f16)lo.y; h[2] = (f16)lo.z; h[3] = (f16)lo.w;
                h[4] = (f16)hi.x; h[5] = (f16)hi.y; h[6] = (f16)hi.z; h[7] = (f16)hi.w;
                *(f16x8v*)&AhS[unit * 8] = h;
            }
            uint4 bv = *(const uint4*)(Bz + (size_t)(n0 + row) * K + k0 + sc8 * 8);
            *(uint4*)&BhS[unit * 8] = bv;
        }
        __syncthreads();
#pragma unroll
        for (int kh = 0; kh < 2; kh++) {
            f16x8v af[4], bf[4];
#pragma unroll
            for (int i = 0; i < 4; i++)
                af[i] = *(const f16x8v*)&AhS[((((kh * 8 + ma + i) * 64 + lane)) ^ (lane >> 4)) * 8];
#pragma unroll
            for (int j = 0; j < 4; j++)
                bf[j] = *(const f16x8v*)&BhS[((((kh * 8 + nb + j) * 64 + lane)) ^ (lane >> 4)) * 8];
#pragma unroll
            for (int i = 0; i < 4; i++)
#pragma unroll
                for (int j = 0; j < 4; j++)
                    acc[i][j] = __builtin_amdgcn_mfma_f32_16x16x32_f16(af[i], bf[j], acc[i][j], 0, 0, 0);
        }
    }

    // epilogue through LDS for coalesced stores. 128x128 f16 = 32 KB = AhS+BhS.
    f16* Ce = AhS;  // alias both buffers (contiguous by declaration order)
    __syncthreads();  // last fragment reads complete before overwrite
    const int cr = lane & 15, qr = lane >> 4;
    const int mwl = (w >> 1) * 64;
    const int nwl = (w & 1) * 64;
#pragma unroll
    for (int i = 0; i < 4; i++) {
#pragma unroll
        for (int j = 0; j < 4; j++) {
            const int col = nwl + j * 16 + cr;
            const float bv = BIAS ? bias[n0 + col] : 0.f;
#pragma unroll
            for (int r = 0; r < 4; r++) {
                const int row = mwl + i * 16 + qr * 4 + r;
                Ce[row * 128 + col] = (f16)(acc[i][j][r] + bv);
            }
        }
    }
    __syncthreads();
#pragma unroll
    for (int r = 0; r < 8; r++) {
        const int f = r * 256 + tid;
        const int row = f >> 4, c16 = f & 15;
        uint4 v = *(const uint4*)&Ce[row * 128 + c16 * 8];
        *(uint4*)(Cz + (size_t)(m0 + row) * 256 + n0 + c16 * 8) = v;
    }
}

// ---------------------------------------------------------------------------
// Per (b,q): cc[i,j] = sum_e ac[b,i,e]*other[b,j,e]; write both softmaxes.
__global__ __launch_bounds__(256) void cc_softmax(const f16* __restrict__ ac,
                                                  const f16* __restrict__ proj1,
                                                  const f16* __restrict__ proj2,
                                                  float* __restrict__ a_att,
                                                  float* __restrict__ o_att) {
    const int b = blockIdx.x, q = blockIdx.y;
    const f16* __restrict__ A = ac + (size_t)b * Ssz * Dsz;
    const f16* __restrict__ Bp = (q ? proj2 : proj1) + (size_t)b * Ssz * Dsz;
    __shared__ __align__(16) float As[16][64];
    __shared__ __align__(16) float Bs[16][64];
    __shared__ float sc[64][65];
    __shared__ float cmax[64], csum[64], rmax[64], rsum[64];
    const int tid = threadIdx.x;
    const int tx = tid & 15, ty = tid >> 4;
    const int lrow = tid >> 2;       // 0..63
    const int lc4 = (tid & 3) * 4;   // 0..12

    float acc[4][4];
#pragma unroll
    for (int i = 0; i < 4; i++)
#pragma unroll
        for (int j = 0; j < 4; j++) acc[i][j] = 0.f;

    for (int k0 = 0; k0 < Dsz; k0 += 16) {
        f16x4 av = *(const f16x4*)(A + lrow * Dsz + k0 + lc4);
        f16x4 bv = *(const f16x4*)(Bp + lrow * Dsz + k0 + lc4);
        __syncthreads();
        As[lc4 + 0][lrow] = (float)av.x;
        As[lc4 + 1][lrow] = (float)av.y;
        As[lc4 + 2][lrow] = (float)av.z;
        As[lc4 + 3][lrow] = (float)av.w;
        Bs[lc4 + 0][lrow] = (float)bv.x;
        Bs[lc4 + 1][lrow] = (float)bv.y;
        Bs[lc4 + 2][lrow] = (float)bv.z;
        Bs[lc4 + 3][lrow] = (float)bv.w;
        __syncthreads();
#pragma unroll
        for (int k = 0; k < 16; k++) {
            float4 a = *(const float4*)&As[k][ty * 4];
            float4 bq = *(const float4*)&Bs[k][tx * 4];
            float a_[4] = {a.x, a.y, a.z, a.w};
            float b_[4] = {bq.x, bq.y, bq.z, bq.w};
#pragma unroll
            for (int i = 0; i < 4; i++)
#pragma unroll
                for (int j = 0; j < 4; j++) acc[i][j] = fmaf(a_[i], b_[j], acc[i][j]);
        }
    }
#pragma unroll
    for (int i = 0; i < 4; i++)
#pragma unroll
        for (int j = 0; j < 4; j++) sc[ty * 4 + i][tx * 4 + j] = acc[i][j];
    __syncthreads();
    if (tid < 64) {
        const int j = tid;
        float m = -1e30f;
        for (int i = 0; i < 64; i++) m = fmaxf(m, sc[i][j]);
        float s = 0.f;
        for (int i = 0; i < 64; i++) s += __expf(sc[i][j] - m);
        cmax[j] = m;
        csum[j] = s;
    } else if (tid < 128) {
        const int i = tid - 64;
        float m = -1e30f;
        for (int j = 0; j < 64; j++) m = fmaxf(m, sc[i][j]);
        float s = 0.f;
        for (int j = 0; j < 64; j++) s += __expf(sc[i][j] - m);
        rmax[i] = m;
        rsum[i] = s;
    }
    __syncthreads();
    const int j = tid & 63;
    const int i00 = tid >> 6;
    float* __restrict__ ap = a_att + (size_t)(q * Bsz + b) * Ssz * Ssz;
    float* __restrict__ op = o_att + (size_t)(q * Bsz + b) * Ssz * Ssz;
    const float cm = cmax[j];
    const float ci = 1.f / csum[j];
    for (int i = i00; i < 64; i += 4) {
        const float v = sc[i][j];
        ap[i * 64 + j] = __expf(v - cm) * ci;
        op[i * 64 + j] = __expf(v - rmax[i]) / rsum[i];
    }
}

// ---------------------------------------------------------------------------
// Per (b,q): part0: fused[b, j, q*512 + d]       = sum_i anchor[i,d]*a_att[i,j] + anchor[j,d]
//            part1: fused[b, i, q*512 + 256 + d] = sum_j other[j,d]*o_att[i,j]  + other[i,d]
__global__ __launch_bounds__(256) void attn_apply(const f16* __restrict__ proj0,
                                                  const f16* __restrict__ proj1,
                                                  const f16* __restrict__ proj2,
                                                  const float* __restrict__ a_att,
                                                  const float* __restrict__ o_att,
                                                  uint16_t* __restrict__ fused) {
    const int b = blockIdx.x, q = blockIdx.y;
    const f16* __restrict__ anchor = proj0 + (size_t)b * Ssz * Dsz;
    const f16* __restrict__ other = (q ? proj2 : proj1) + (size_t)b * Ssz * Dsz;
    __shared__ __align__(16) float att[64][68];
    __shared__ __align__(16) float Bs[16][256];
    const int tid = threadIdx.x;
    const int tx = tid & 31;   // d-tile (8 wide) -> 256
    const int ty = tid >> 5;   // 0..7 token-tile (8 wide) -> 64

    for (int part = 0; part < 2; part++) {
        const float4* __restrict__ attg =
            (const float4*)((part == 0 ? a_att : o_att) + (size_t)(q * Bsz + b) * 4096);
        const f16* __restrict__ Bmat = (part == 0) ? anchor : other;
        __syncthreads();  // protect att/Bs reuse from previous part's compute
#pragma unroll
        for (int t = tid, r = 0; r < 4; t += 256, r++) {
            float4 v = attg[t];
            const int i = t >> 4, j4 = (t & 15) * 4;
            if (part == 0) {  // As[k=i][m=j] = a_att[i][j]
                att[i][j4 + 0] = v.x;
                att[i][j4 + 1] = v.y;
                att[i][j4 + 2] = v.z;
                att[i][j4 + 3] = v.w;
            } else {          // As[k=j][m=i] = o_att[i][j] transposed
                att[j4 + 0][i] = v.x;
                att[j4 + 1][i] = v.y;
                att[j4 + 2][i] = v.z;
                att[j4 + 3][i] = v.w;
            }
        }
        float acc[8][8];
#pragma unroll
        for (int i = 0; i < 8; i++)
#pragma unroll
            for (int j = 0; j < 8; j++) acc[i][j] = 0.f;

        for (int k0 = 0; k0 < 64; k0 += 16) {
            f16x4 bvr[4];
#pragma unroll
            for (int t = tid, r = 0; r < 4; t += 256, r++)
                bvr[r] = *(const f16x4*)(Bmat + (size_t)((t >> 6) + k0) * Dsz + (t & 63) * 4);
            __syncthreads();  // prev compute done (and att stores visible on first iter)
#pragma unroll
            for (int t = tid, r = 0; r < 4; t += 256, r++) {
                float4 fv;
                fv.x = (float)bvr[r].x;
                fv.y = (float)bvr[r].y;
                fv.z = (float)bvr[r].z;
                fv.w = (float)bvr[r].w;
                *(float4*)&Bs[t >> 6][(t & 63) * 4] = fv;
            }
            __syncthreads();
#pragma unroll
            for (int k = 0; k < 16; k++) {
                const int kk = k0 + k;
                float4 a0 = *(const float4*)&att[kk][ty * 8];
                float4 a1 = *(const float4*)&att[kk][ty * 8 + 4];
                float4 b0 = *(const float4*)&Bs[k][tx * 8];
                float4 b1 = *(const float4*)&Bs[k][tx * 8 + 4];
                float a_[8] = {a0.x, a0.y, a0.z, a0.w, a1.x, a1.y, a1.z, a1.w};
                float b_[8] = {b0.x, b0.y, b0.z, b0.w, b1.x, b1.y, b1.z, b1.w};
#pragma unroll
                for (int i = 0; i < 8; i++)
#pragma unroll
                    for (int j = 0; j < 8; j++) acc[i][j] = fmaf(a_[i], b_[j], acc[i][j]);
            }
        }
        const int c0 = q * 512 + part * 256 + tx * 8;
#pragma unroll
        for (int r = 0; r < 8; r++) {
            const int s = ty * 8 + r;  // output token index
            f16x8v rv = *(const f16x8v*)(Bmat + (size_t)s * Dsz + tx * 8);
            uint4 pk;
            pk.x = f2bf(acc[r][0] + (float)rv[0]) | (f2bf(acc[r][1] + (float)rv[1]) << 16);
            pk.y = f2bf(acc[r][2] + (float)rv[2]) | (f2bf(acc[r][3] + (float)rv[3]) << 16);
            pk.z = f2bf(acc[r][4] + (float)rv[4]) | (f2bf(acc[r][5] + (float)rv[5]) << 16);
            pk.w = f2bf(acc[r][6] + (float)rv[6]) | (f2bf(acc[r][7] + (float)rv[7]) << 16);
            *(uint4*)(fused + (size_t)(b * 64 + s) * FIN + c0) = pk;
        }
    }
}

// ---------------------------------------------------------------------------
// h[m,o] = sum_c fused[m,c]*Wb[o,c] + bb[o]; LayerNorm over o (64); ReLU.
__global__ __launch_bounds__(256) void final_ln(const uint16_t* __restrict__ fused,
                                                const float* __restrict__ Wb,
                                                const float* __restrict__ bb,
                                                const float* __restrict__ gamma,
                                                const float* __restrict__ beta,
                                                float* __restrict__ out) {
    const int m0 = blockIdx.x * 64;
    __shared__ __align__(16) float As[16][64];
    __shared__ __align__(16) float Bs[16][64];
    __shared__ float sh[64][65];
    __shared__ float smu[64], sinv[64];
    const int tid = threadIdx.x;
    const int tx = tid & 15, ty = tid >> 4;
    const int lrow = tid >> 2;      // 0..63
    const int lc4 = (tid & 3) * 4;  // 0..12

    float acc[4][4];
#pragma unroll
    for (int i = 0; i < 4; i++)
#pragma unroll
        for (int j = 0; j < 4; j++) acc[i][j] = 0.f;

    for (int k0 = 0; k0 < FIN; k0 += 16) {
        ushort4 av = *(const ushort4*)(fused + (size_t)(m0 + lrow) * FIN + k0 + lc4);
        float4 bv = *(const float4*)(Wb + (size_t)lrow * FIN + k0 + lc4);
        __syncthreads();
        As[lc4 + 0][lrow] = __uint_as_float((uint32_t)av.x << 16);
        As[lc4 + 1][lrow] = __uint_as_float((uint32_t)av.y << 16);
        As[lc4 + 2][lrow] = __uint_as_float((uint32_t)av.z << 16);
        As[lc4 + 3][lrow] = __uint_as_float((uint32_t)av.w << 16);
        Bs[lc4 + 0][lrow] = bv.x;
        Bs[lc4 + 1][lrow] = bv.y;
        Bs[lc4 + 2][lrow] = bv.z;
        Bs[lc4 + 3][lrow] = bv.w;
        __syncthreads();
#pragma unroll
        for (int k = 0; k < 16; k++) {
            float4 a = *(const float4*)&As[k][ty * 4];
            float4 bq = *(const float4*)&Bs[k][tx * 4];
            float a_[4] = {a.x, a.y, a.z, a.w};
            float b_[4] = {bq.x, bq.y, bq.z, bq.w};
#pragma unroll
            for (int i = 0; i < 4; i++)
#pragma unroll
                for (int j = 0; j < 4; j++) acc[i][j] = fmaf(a_[i], b_[j], acc[i][j]);
        }
    }
#pragma unroll
    for (int i = 0; i < 4; i++)
#pragma unroll
        for (int j = 0; j < 4; j++) sh[ty * 4 + i][tx * 4 + j] = acc[i][j] + bb[tx * 4 + j];
    __syncthreads();
    if (tid < 64) {
        const int m = tid;
        float s = 0.f, ss = 0.f;
        for (int o = 0; o < 64; o++) {
            const float v = sh[m][o];
            s += v;
            ss += v * v;
        }
        const float mu = s * (1.f / 64.f);
        const float var = ss * (1.f / 64.f) - mu * mu;
        smu[m] = mu;
        sinv[m] = rsqrtf(var + 1e-5f);
    }
    __syncthreads();
    const int o = tid & 63;
    const int i00 = tid >> 6;
    for (int m = i00; m < 64; m += 4) {
        float v = (sh[m][o] - smu[m]) * sinv[m] * gamma[o] + beta[o];
        out[(size_t)(m0 + m) * 64 + o] = fmaxf(v, 0.f);
    }
}

extern "C" void kernel_launch(void* const* d_in, const int* in_sizes, int n_in,
                              void* d_out, int out_size, void* d_ws, size_t ws_size,
                              hipStream_t stream) {
    const float* latent0 = (const float*)d_in[0];
    const float* Wp0 = (const float*)d_in[1];
    const float* bp0 = (const float*)d_in[2];
    const float* latent1 = (const float*)d_in[3];
    const float* Wp1 = (const float*)d_in[4];
    const float* bp1 = (const float*)d_in[5];
    const float* latent2 = (const float*)d_in[6];
    const float* Wp2 = (const float*)d_in[7];
    const float* bp2 = (const float*)d_in[8];
    const float* corr = (const float*)d_in[9];
    const float* Wb = (const float*)d_in[10];
    const float* bb = (const float*)d_in[11];
    const float* gamma = (const float*)d_in[12];
    const float* beta = (const float*)d_in[13];

    char* ws = (char*)d_ws;
    f16* proj_h = (f16*)ws;                               // 3 * 16 MB
    f16* ac_h = (f16*)(ws + 48ull * 1024 * 1024);         // 16 MB
    float* a_att = (float*)(ws + 64ull * 1024 * 1024);    // 16 MB
    float* o_att = (float*)(ws + 80ull * 1024 * 1024);    // 16 MB
    uint16_t* fused = (uint16_t*)(ws + 96ull * 1024 * 1024);  // 64 MB
    f16* Wph = (f16*)(ws + 160ull * 1024 * 1024);         // 1.125 MB
    f16* corrT = (f16*)(ws + 162ull * 1024 * 1024);       // 128 KB

    float* out = (float*)d_out;
    dim3 blk(256);

    // pre-convert weights
    prep<<<2304, blk, 0, stream>>>(Wp0, Wp1, Wp2, corr, Wph, corrT);

    // projections: proj_h[z] = latent_z @ Wp_z^T + bp_z   (fp16 MFMA)
    mfma_gemm<false, true><<<dim3(2, 256, 3), blk, 0, stream>>>(
        latent0, latent1, latent2, (const f16*)nullptr, Wph, bp0, bp1, bp2, proj_h, Esz);

    // ac = proj0 @ corr  (B = corrT [e][d] f16)
    mfma_gemm<true, false><<<dim3(2, 256, 1), blk, 0, stream>>>(
        (const float*)nullptr, (const float*)nullptr, (const float*)nullptr, proj_h,
        corrT, (const float*)nullptr, (const float*)nullptr, (const float*)nullptr,
        ac_h, Dsz);

    const f16* proj1_h = proj_h + (size_t)MROWS * 256;
    const f16* proj2_h = proj_h + 2ull * MROWS * 256;

    // cc + both softmaxes
    cc_softmax<<<dim3(Bsz, 2), blk, 0, stream>>>(ac_h, proj1_h, proj2_h, a_att, o_att);

    // attention apply -> fused (bf16)
    attn_apply<<<dim3(Bsz, 2), blk, 0, stream>>>(proj_h, proj1_h, proj2_h, a_att, o_att, fused);

    // bottleneck GEMM + LayerNorm + ReLU
    final_ln<<<MROWS / 64, blk, 0, stream>>>(fused, Wb, bb, gamma, beta, out);

    (void)in_sizes; (void)n_in; (void)out_size; (void)ws_size;
}